// Round 7
// baseline (158.561 us; speedup 1.0000x reference)
//
#include <hip/hip_runtime.h>
#include <hip/hip_fp16.h>

#define B 64
#define N 4096
#define M 128

constexpr int T    = 512;           // 8 waves
constexpr int CPB  = 8;             // channels per block -> 4 packed complex FFTs
constexpr int NF   = 4;
constexpr int NGB  = M / CPB;       // 16 channel groups
constexpr int NWG  = B * NGB;       // 1024 blocks, 2 co-resident/CU, 2 rounds

// LDS slot: plane f (stride 4096 half2 = bank-aligned), 5-bit XOR fold of the
// index + per-plane bank rotation (f<<3) so planes don't collide.
__device__ __forceinline__ int slot(int f, int p) {
    int low = (p ^ (p >> 5) ^ (p >> 9) ^ (f << 3)) & 31;
    return (f << 12) + (p & ~31) + low;
}
// octal-digit reverse of 12-bit index (DIF output slot of frequency k)
__device__ __forceinline__ int rev12(int k) {
    return ((k & 7) << 9) | (((k >> 3) & 7) << 6) | (((k >> 6) & 7) << 3) | ((k >> 9) & 7);
}

__device__ __forceinline__ float2 cadd(float2 a, float2 b){ return make_float2(a.x+b.x, a.y+b.y); }
__device__ __forceinline__ float2 csub(float2 a, float2 b){ return make_float2(a.x-b.x, a.y-b.y); }
__device__ __forceinline__ float2 cmul(float2 a, float2 b){ return make_float2(a.x*b.x - a.y*b.y, a.x*b.y + a.y*b.x); }
__device__ __forceinline__ float2 mulnegi(float2 a){ return make_float2(a.y, -a.x); }
__device__ __forceinline__ float2 muli(float2 a)  { return make_float2(-a.y, a.x); }
__device__ __forceinline__ float2 cis(float ang){ float s, c; __sincosf(ang, &s, &c); return make_float2(c, s); }
__device__ __forceinline__ float2 h2f(__half2 h){ return __half22float2(h); }
__device__ __forceinline__ __half2 f2h(float2 v){ return __floats2half2_rn(v.x, v.y); }

// forward DFT8 in place (W8 = e^{-i pi/4})
__device__ __forceinline__ void dft8(float2 t[8]) {
    float2 e0=cadd(t[0],t[4]), e1=csub(t[0],t[4]);
    float2 e2=cadd(t[2],t[6]), e3=csub(t[2],t[6]);
    float2 E0=cadd(e0,e2), E2=csub(e0,e2);
    float2 E1=cadd(e1,mulnegi(e3)), E3=cadd(e1,muli(e3));
    float2 o0=cadd(t[1],t[5]), o1=csub(t[1],t[5]);
    float2 o2=cadd(t[3],t[7]), o3=csub(t[3],t[7]);
    float2 O0=cadd(o0,o2), O2=csub(o0,o2);
    float2 O1=cadd(o1,mulnegi(o3)), O3=cadd(o1,muli(o3));
    const float C = 0.70710678118654752f;
    float2 w1O1 = make_float2(C*(O1.x+O1.y), C*(O1.y-O1.x));
    float2 w2O2 = mulnegi(O2);
    float2 w3O3 = make_float2(C*(O3.y-O3.x), -C*(O3.x+O3.y));
    t[0]=cadd(E0,O0);   t[4]=csub(E0,O0);
    t[1]=cadd(E1,w1O1); t[5]=csub(E1,w1O1);
    t[2]=cadd(E2,w2O2); t[6]=csub(E2,w2O2);
    t[3]=cadd(E3,w3O3); t[7]=csub(E3,w3O3);
}

// One radix-8 DIF stage, span S. In-place on identical slots per task.
template<int S>
__device__ __forceinline__ void stage(__half2* z, int tid) {
    #pragma unroll
    for (int it = 0; it < 4; ++it) {
        const int q  = tid + (it << 9);    // 0..2047
        const int f  = q >> 9;             // FFT id 0..3
        const int qq = q & 511;
        int G, j;
        if      (S == 512) { G = 0;                j = qq;      }
        else if (S == 64)  { G = (qq >> 6) << 9;   j = qq & 63; }
        else if (S == 8)   { G = (qq >> 3) << 6;   j = qq & 7;  }
        else               { G = qq << 3;          j = 0;       }
        const int nbase = G + j;
        int idx[8];
        #pragma unroll
        for (int c = 0; c < 8; ++c) idx[c] = slot(f, nbase + c * S);
        float2 r[8];
        #pragma unroll
        for (int c = 0; c < 8; ++c) r[c] = h2f(z[idx[c]]);
        dft8(r);
        if (S > 1) {
            float2 w1 = cis(-6.2831853071795864f * (float)j / (float)(8 * S));
            float2 w = w1;
            #pragma unroll
            for (int k = 1; k < 8; ++k) { r[k] = cmul(r[k], w); w = cmul(w, w1); }
        }
        #pragma unroll
        for (int c = 0; c < 8; ++c) z[idx[c]] = f2h(r[c]);
    }
}

__global__ __launch_bounds__(T, 4)
void fft_one(const float* __restrict__ x, float* __restrict__ out) {
    extern __shared__ __half2 z[];   // [NF][4096] folded, 64 KiB -> 2 blocks/CU

    // decode so all 16 channel-groups of batch b share one XCD (bid%8 == b&7)
    const int bid = blockIdx.x;
    const int b  = ((bid >> 7) << 3) | (bid & 7);
    const int g  = (bid >> 3) & 15;
    const int m0 = g * CPB;
    const float* xb = x + (size_t)b * N * M + m0;
    const int tid = threadIdx.x;

    // ---- load: 8192 float4 tasks (row n, quad c); pack ch pairs as half2 cplx ----
    #pragma unroll
    for (int it = 0; it < 16; ++it) {
        int i = tid + (it << 9);
        int n = i >> 1, c = i & 1;
        float4 v = *(const float4*)(xb + (size_t)n * M + (c << 2));
        z[slot(2 * c,     n)] = f2h(make_float2(v.x, v.y));
        z[slot(2 * c + 1, n)] = f2h(make_float2(v.z, v.w));
    }
    __syncthreads();

    // ---- 4 radix-8 DIF stages: natural in -> digit-reversed out ----
    stage<512>(z, tid); __syncthreads();
    stage<64 >(z, tid); __syncthreads();
    stage<8  >(z, tid); __syncthreads();
    stage<1  >(z, tid); __syncthreads();

    // ---- Hermitian unpack (freq k at slot rev12(k)) + coalesced stores ----
    float* outRe = out;
    float* outIm = out + (size_t)B * N * M;
    const size_t rbase = (size_t)b * N * M + m0;
    #pragma unroll
    for (int it = 0; it < 16; ++it) {
        int u = tid + (it << 9);
        int k = u >> 1, c = u & 1;
        int kk = (N - k) & (N - 1);
        int sk = rev12(k), smk = rev12(kk);
        float2 Zk0 = h2f(z[slot(2 * c,     sk )]);
        float2 Zm0 = h2f(z[slot(2 * c,     smk)]);
        float2 Zk1 = h2f(z[slot(2 * c + 1, sk )]);
        float2 Zm1 = h2f(z[slot(2 * c + 1, smk)]);
        float4 re, im;
        re.x = 0.5f * (Zk0.x + Zm0.x); im.x = 0.5f * (Zk0.y - Zm0.y);
        re.y = 0.5f * (Zk0.y + Zm0.y); im.y = 0.5f * (Zm0.x - Zk0.x);
        re.z = 0.5f * (Zk1.x + Zm1.x); im.z = 0.5f * (Zk1.y - Zm1.y);
        re.w = 0.5f * (Zk1.y + Zm1.y); im.w = 0.5f * (Zm1.x - Zk1.x);
        *(float4*)(outRe + rbase + (size_t)k * M + (c << 2)) = re;
        *(float4*)(outIm + rbase + (size_t)k * M + (c << 2)) = im;
    }
}

extern "C" void kernel_launch(void* const* d_in, const int* in_sizes, int n_in,
                              void* d_out, int out_size, void* d_ws, size_t ws_size,
                              hipStream_t stream) {
    const float* x = (const float*)d_in[0];
    float* out = (float*)d_out;
    const int lds_bytes = NF * N * (int)sizeof(__half2);   // 65536
    hipFuncSetAttribute((const void*)fft_one,
                        hipFuncAttributeMaxDynamicSharedMemorySize, lds_bytes);
    fft_one<<<NWG, T, lds_bytes, stream>>>(x, out);
}